// Round 6
// baseline (253.230 us; speedup 1.0000x reference)
//
#include <hip/hip_runtime.h>
#include <math.h>

#define H 128
#define NF 100000
#define NC 25000
#define TM 64

typedef __bf16 bf16;
typedef bf16 bf16x8 __attribute__((ext_vector_type(8)));
typedef bf16 bf16x4 __attribute__((ext_vector_type(4)));
typedef float f32x4 __attribute__((ext_vector_type(4)));

#define MFMA(a, b, c) __builtin_amdgcn_mfma_f32_16x16x32_bf16((a), (b), (c), 0, 0, 0)

// ws layout in bf16 elements:
//   0      WT1hi [128][256]   (W1^T over k<256; W1 row 256 folded as rank-1 into init)
//   32768  WT1lo
//   65536  WT2hi [128][128]
//   81920  WT2lo
//   98304  WT3hi
//   114688 WT3lo

__global__ void prep_w(const float* __restrict__ W1, const float* __restrict__ W2,
                       const float* __restrict__ W3, bf16* __restrict__ ws)
{
    int i = blockIdx.x * 256 + threadIdx.x;   // 0..65535, grid exact
    float v; bf16* hp; bf16* lp; int idx;
    if (i < 32768) {                          // W1^T: n = i>>8, k = i&255
        int n = i >> 8, k = i & 255;
        v = W1[k * H + n]; hp = ws; lp = ws + 32768; idx = i;
    } else if (i < 49152) {                   // W2^T
        int j = i - 32768, n = j >> 7, k = j & 127;
        v = W2[k * H + n]; hp = ws + 65536; lp = ws + 81920; idx = j;
    } else {                                  // W3^T
        int j = i - 49152, n = j >> 7, k = j & 127;
        v = W3[k * H + n]; hp = ws + 98304; lp = ws + 114688; idx = j;
    }
    bf16 h = (bf16)v;
    hp[idx] = h;
    lp[idx] = (bf16)(v - (float)h);
}

__device__ __forceinline__ float silu_f(float v) {
    return v / (1.0f + __expf(-v));
}

// element index into a [TM][H] bf16 plane with 16B-slot XOR swizzle
__device__ __forceinline__ int swz(int row, int col) {
    return row * H + (((col >> 3) ^ (row & 7)) << 3) + (col & 7);
}

// A-fragment read from LDS h-plane: row, k = 8*lane-group offset (mult of 8)
__device__ __forceinline__ bf16x8 ldsA(const bf16* __restrict__ p, int row, int k) {
    int idx = row * H + ((((k >> 3) ^ (row & 7))) << 3);
    return *(const bf16x8*)(p + idx);
}

// split 8 f32 into bf16 hi/lo fragments
__device__ __forceinline__ void split8(float4 v0, float4 v1, bf16x8& hi, bf16x8& lo) {
    float a[8] = {v0.x, v0.y, v0.z, v0.w, v1.x, v1.y, v1.z, v1.w};
    #pragma unroll
    for (int i = 0; i < 8; ++i) {
        bf16 h = (bf16)a[i];
        hi[i] = h;
        lo[i] = (bf16)(a[i] - (float)h);
    }
}

// K=128 GEMM from LDS h-planes, 3-product split accumulation
__device__ __forceinline__ void gemm3_lds(const bf16* __restrict__ Ah, const bf16* __restrict__ Al,
                                          const bf16* __restrict__ Bh, const bf16* __restrict__ Bl,
                                          int wRow, int wCol, int lr, int lg, f32x4 acc[2][4])
{
    #pragma unroll
    for (int kk = 0; kk < 4; ++kk) {
        const int k = kk * 32 + (lg << 3);
        bf16x8 a0h = ldsA(Ah, wRow + lr, k);
        bf16x8 a0l = ldsA(Al, wRow + lr, k);
        bf16x8 a1h = ldsA(Ah, wRow + 16 + lr, k);
        bf16x8 a1l = ldsA(Al, wRow + 16 + lr, k);
        #pragma unroll
        for (int nt = 0; nt < 4; ++nt) {
            int off = (wCol + nt * 16 + lr) * 128 + k;
            bf16x8 bh = *(const bf16x8*)(Bh + off);
            bf16x8 bl = *(const bf16x8*)(Bl + off);
            acc[0][nt] = MFMA(a0h, bh, acc[0][nt]);
            acc[0][nt] = MFMA(a0l, bh, acc[0][nt]);
            acc[0][nt] = MFMA(a0h, bl, acc[0][nt]);
            acc[1][nt] = MFMA(a1h, bh, acc[1][nt]);
            acc[1][nt] = MFMA(a1l, bh, acc[1][nt]);
            acc[1][nt] = MFMA(a1h, bl, acc[1][nt]);
        }
    }
}

// silu + split + swizzled store of a wave's 32x64 result into LDS h-planes
__device__ __forceinline__ void store_h(const f32x4 acc[2][4], bf16* __restrict__ Dh,
                                        bf16* __restrict__ Dl, int wRow, int wCol, int lr, int lg)
{
    #pragma unroll
    for (int mt = 0; mt < 2; ++mt)
        #pragma unroll
        for (int nt = 0; nt < 4; ++nt)
            #pragma unroll
            for (int r = 0; r < 4; ++r) {
                int row = wRow + mt * 16 + lg * 4 + r;
                int col = wCol + nt * 16 + lr;
                float v = silu_f(acc[mt][nt][r]);
                bf16 h = (bf16)v;
                int idx = swz(row, col);
                Dh[idx] = h;
                Dl[idx] = (bf16)(v - (float)h);
            }
}

__global__ __launch_bounds__(256, 4)
void fused_mlp_mfma(const float* __restrict__ x,     // [2][25000][128]
                    const float* __restrict__ xsc,   // [2][100000][128]
                    const int*   __restrict__ f2c,   // [100000]
                    const float* __restrict__ dist,  // [100000]
                    const float* __restrict__ W1,    // [257][128] (row 256 used)
                    const float* __restrict__ b1,
                    const float* __restrict__ b2,
                    const float* __restrict__ b3,
                    const bf16*  __restrict__ ws,
                    float* __restrict__ out)         // [200000][128]
{
    __shared__ __align__(16) bf16 sHh[TM * H], sHl[TM * H];  // 32 KB total
    __shared__ float sD[TM];
    __shared__ int   sCI[TM];

    const int t = threadIdx.x;
    const int l = t & 63, w = t >> 6;
    const int wRow = (w >> 1) * 32;      // 0 or 32
    const int wCol = (w & 1) * 64;       // 0 or 64
    const int lr = l & 15, lg = l >> 4;
    const long long R0 = (long long)blockIdx.x * TM;

    // ---- per-row metadata ----
    if (t < TM) {
        long long Rs = R0 + t;
        int bb = Rs >= NF;
        int nn = (int)(Rs - (long long)bb * NF);
        sCI[t] = f2c[nn];
        sD[t]  = dist[nn];
    }
    __syncthreads();                               // barrier 1

    const bf16* WT1h = ws;
    const bf16* WT1l = ws + 32768;
    const bf16* WT2h = ws + 65536;
    const bf16* WT2l = ws + 81920;
    const bf16* WT3h = ws + 98304;
    const bf16* WT3l = ws + 114688;

    // ---- layer 1: acc = b1 + d*W1[256] + concat(xg,xs) @ W1[0:256] ----
    // A-fragments loaded per-lane directly from global (no LDS staging).
    f32x4 acc[2][4];
    #pragma unroll
    for (int nt = 0; nt < 4; ++nt) {
        int col = wCol + nt * 16 + lr;
        float bc = b1[col];
        float wc = W1[256 * H + col];
        #pragma unroll
        for (int mt = 0; mt < 2; ++mt)
            #pragma unroll
            for (int r = 0; r < 4; ++r)
                acc[mt][nt][r] = bc + sD[wRow + mt * 16 + lg * 4 + r] * wc;
    }

    // this lane's two A-rows
    const long long Rs0 = R0 + wRow + lr;
    const long long Rs1 = R0 + wRow + 16 + lr;
    const int bb0 = Rs0 >= NF, bb1 = Rs1 >= NF;
    const float* xg0 = x + ((long long)bb0 * NC + sCI[wRow + lr]) * H;
    const float* xg1 = x + ((long long)bb1 * NC + sCI[wRow + 16 + lr]) * H;
    const float* xs0 = xsc + Rs0 * H;
    const float* xs1 = xsc + Rs1 * H;

    // xg part: W1^T k in [0,128)
    #pragma unroll 2
    for (int kk = 0; kk < 4; ++kk) {
        const int kc = kk * 32 + (lg << 3);        // col in source row & k in W1T
        bf16x8 a0h, a0l, a1h, a1l;
        split8(*(const float4*)(xg0 + kc), *(const float4*)(xg0 + kc + 4), a0h, a0l);
        split8(*(const float4*)(xg1 + kc), *(const float4*)(xg1 + kc + 4), a1h, a1l);
        #pragma unroll
        for (int nt = 0; nt < 4; ++nt) {
            int off = (wCol + nt * 16 + lr) * 256 + kc;
            bf16x8 bh = *(const bf16x8*)(WT1h + off);
            bf16x8 bl = *(const bf16x8*)(WT1l + off);
            acc[0][nt] = MFMA(a0h, bh, acc[0][nt]);
            acc[0][nt] = MFMA(a0l, bh, acc[0][nt]);
            acc[0][nt] = MFMA(a0h, bl, acc[0][nt]);
            acc[1][nt] = MFMA(a1h, bh, acc[1][nt]);
            acc[1][nt] = MFMA(a1l, bh, acc[1][nt]);
            acc[1][nt] = MFMA(a1h, bl, acc[1][nt]);
        }
    }
    // xs part: W1^T k in [128,256)
    #pragma unroll 2
    for (int kk = 0; kk < 4; ++kk) {
        const int kc = kk * 32 + (lg << 3);
        bf16x8 a0h, a0l, a1h, a1l;
        split8(*(const float4*)(xs0 + kc), *(const float4*)(xs0 + kc + 4), a0h, a0l);
        split8(*(const float4*)(xs1 + kc), *(const float4*)(xs1 + kc + 4), a1h, a1l);
        #pragma unroll
        for (int nt = 0; nt < 4; ++nt) {
            int off = (wCol + nt * 16 + lr) * 256 + 128 + kc;
            bf16x8 bh = *(const bf16x8*)(WT1h + off);
            bf16x8 bl = *(const bf16x8*)(WT1l + off);
            acc[0][nt] = MFMA(a0h, bh, acc[0][nt]);
            acc[0][nt] = MFMA(a0l, bh, acc[0][nt]);
            acc[0][nt] = MFMA(a0h, bl, acc[0][nt]);
            acc[1][nt] = MFMA(a1h, bh, acc[1][nt]);
            acc[1][nt] = MFMA(a1l, bh, acc[1][nt]);
            acc[1][nt] = MFMA(a1h, bl, acc[1][nt]);
        }
    }

    store_h(acc, sHh, sHl, wRow, wCol, lr, lg);    // h1 -> sH (first write, no reader yet)
    __syncthreads();                               // barrier 2: h1 visible

    // ---- layer 2 ----
    #pragma unroll
    for (int nt = 0; nt < 4; ++nt) {
        float bc = b2[wCol + nt * 16 + lr];
        #pragma unroll
        for (int mt = 0; mt < 2; ++mt)
            #pragma unroll
            for (int r = 0; r < 4; ++r)
                acc[mt][nt][r] = bc;
    }
    gemm3_lds(sHh, sHl, WT2h, WT2l, wRow, wCol, lr, lg, acc);
    __syncthreads();                               // barrier 3: all done reading h1

    store_h(acc, sHh, sHl, wRow, wCol, lr, lg);    // h2 -> sH
    __syncthreads();                               // barrier 4: h2 visible

    // ---- layer 3 ----
    #pragma unroll
    for (int nt = 0; nt < 4; ++nt) {
        float bc = b3[wCol + nt * 16 + lr];
        #pragma unroll
        for (int mt = 0; mt < 2; ++mt)
            #pragma unroll
            for (int r = 0; r < 4; ++r)
                acc[mt][nt][r] = bc;
    }
    gemm3_lds(sHh, sHl, WT3h, WT3l, wRow, wCol, lr, lg, acc);

    // ---- store out ----
    #pragma unroll
    for (int mt = 0; mt < 2; ++mt)
        #pragma unroll
        for (int nt = 0; nt < 4; ++nt)
            #pragma unroll
            for (int r = 0; r < 4; ++r) {
                long long row = R0 + wRow + mt * 16 + lg * 4 + r;
                int col = wCol + nt * 16 + lr;
                out[row * H + col] = acc[mt][nt][r];
            }
}

extern "C" void kernel_launch(void* const* d_in, const int* in_sizes, int n_in,
                              void* d_out, int out_size, void* d_ws, size_t ws_size,
                              hipStream_t stream)
{
    const float* x    = (const float*)d_in[0];
    const float* xsc  = (const float*)d_in[1];
    const int*   f2c  = (const int*)d_in[2];
    const float* dist = (const float*)d_in[3];
    const float* W1   = (const float*)d_in[4];
    const float* b1   = (const float*)d_in[5];
    const float* W2   = (const float*)d_in[6];
    const float* b2   = (const float*)d_in[7];
    const float* W3   = (const float*)d_in[8];
    const float* b3   = (const float*)d_in[9];
    bf16* ws = (bf16*)d_ws;

    prep_w<<<256, 256, 0, stream>>>(W1, W2, W3, ws);

    const int n_rows = 2 * NF;                    // 200000
    dim3 grid(n_rows / TM);                       // 3125
    fused_mlp_mfma<<<grid, 256, 0, stream>>>(x, xsc, f2c, dist, W1, b1, b2, b3,
                                             ws, (float*)d_out);
}

// Round 7
// 163.386 us; speedup vs baseline: 1.5499x; 1.5499x over previous
//
#include <hip/hip_runtime.h>
#include <math.h>

#define H 128
#define NF 100000
#define NC 25000
#define TM 64

typedef _Float16 f16;
typedef f16 f16x8 __attribute__((ext_vector_type(8)));
typedef float f32x4 __attribute__((ext_vector_type(4)));

#define MFMA16(a, b, c) __builtin_amdgcn_mfma_f32_16x16x32_f16((a), (b), (c), 0, 0, 0)

// ws layout in f16 elements (single plane, f16 weights):
//   0      WT1 [128][256]  (W1^T over k<256; W1 row 256 folded as rank-1 f32 into init)
//   32768  WT2 [128][128]
//   49152  WT3 [128][128]
// total 65536 f16 = 128 KiB

__global__ void prep_w(const float* __restrict__ W1, const float* __restrict__ W2,
                       const float* __restrict__ W3, f16* __restrict__ ws)
{
    int i = blockIdx.x * 256 + threadIdx.x;   // 0..65535, grid exact
    if (i < 32768) {                          // W1^T: n = i>>8, k = i&255
        int n = i >> 8, k = i & 255;
        ws[i] = (f16)W1[k * H + n];
    } else if (i < 49152) {                   // W2^T
        int j = i - 32768, n = j >> 7, k = j & 127;
        ws[32768 + j] = (f16)W2[k * H + n];
    } else {                                  // W3^T
        int j = i - 49152, n = j >> 7, k = j & 127;
        ws[49152 + j] = (f16)W3[k * H + n];
    }
}

__device__ __forceinline__ float silu_f(float v) {
    return v / (1.0f + __expf(-v));
}

// element index into a [TM][H] f16 plane with 16B-slot XOR swizzle
__device__ __forceinline__ int swz(int row, int col) {
    return row * H + (((col >> 3) ^ (row & 7)) << 3) + (col & 7);
}

// A-fragment read from LDS h-plane: row, k (mult of 8)
__device__ __forceinline__ f16x8 ldsA(const f16* __restrict__ p, int row, int k) {
    int idx = row * H + ((((k >> 3) ^ (row & 7))) << 3);
    return *(const f16x8*)(p + idx);
}

// split 8 f32 into f16 hi/lo fragments (hi + lo reconstructs a to ~2^-22 rel)
__device__ __forceinline__ void split8(float4 v0, float4 v1, f16x8& hi, f16x8& lo) {
    float a[8] = {v0.x, v0.y, v0.z, v0.w, v1.x, v1.y, v1.z, v1.w};
    #pragma unroll
    for (int i = 0; i < 8; ++i) {
        f16 h = (f16)a[i];
        hi[i] = h;
        lo[i] = (f16)(a[i] - (float)h);
    }
}

// K=128 GEMM from LDS h-planes, 2-product split accumulation (w is single-plane f16)
__device__ __forceinline__ void gemm2_lds(const f16* __restrict__ Ah, const f16* __restrict__ Al,
                                          const f16* __restrict__ B,
                                          int wRow, int wCol, int lr, int lg, f32x4 acc[2][4])
{
    #pragma unroll
    for (int kk = 0; kk < 4; ++kk) {
        const int k = kk * 32 + (lg << 3);
        f16x8 a0h = ldsA(Ah, wRow + lr, k);
        f16x8 a0l = ldsA(Al, wRow + lr, k);
        f16x8 a1h = ldsA(Ah, wRow + 16 + lr, k);
        f16x8 a1l = ldsA(Al, wRow + 16 + lr, k);
        #pragma unroll
        for (int nt = 0; nt < 4; ++nt) {
            int off = (wCol + nt * 16 + lr) * 128 + k;
            f16x8 w = *(const f16x8*)(B + off);
            acc[0][nt] = MFMA16(a0h, w, acc[0][nt]);
            acc[0][nt] = MFMA16(a0l, w, acc[0][nt]);
            acc[1][nt] = MFMA16(a1h, w, acc[1][nt]);
            acc[1][nt] = MFMA16(a1l, w, acc[1][nt]);
        }
    }
}

// silu + split + swizzled store of a wave's 32x64 result into LDS h-planes
__device__ __forceinline__ void store_h(const f32x4 acc[2][4], f16* __restrict__ Dh,
                                        f16* __restrict__ Dl, int wRow, int wCol, int lr, int lg)
{
    #pragma unroll
    for (int mt = 0; mt < 2; ++mt)
        #pragma unroll
        for (int nt = 0; nt < 4; ++nt)
            #pragma unroll
            for (int r = 0; r < 4; ++r) {
                int row = wRow + mt * 16 + lg * 4 + r;
                int col = wCol + nt * 16 + lr;
                float v = silu_f(acc[mt][nt][r]);
                f16 h = (f16)v;
                int idx = swz(row, col);
                Dh[idx] = h;
                Dl[idx] = (f16)(v - (float)h);
            }
}

__global__ __launch_bounds__(256, 4)
void fused_mlp_mfma(const float* __restrict__ x,     // [2][25000][128]
                    const float* __restrict__ xsc,   // [2][100000][128]
                    const int*   __restrict__ f2c,   // [100000]
                    const float* __restrict__ dist,  // [100000]
                    const float* __restrict__ W1,    // [257][128] (row 256 used)
                    const float* __restrict__ b1,
                    const float* __restrict__ b2,
                    const float* __restrict__ b3,
                    const f16*   __restrict__ ws,
                    float* __restrict__ out)         // [200000][128]
{
    __shared__ __align__(16) f16 sHh[TM * H], sHl[TM * H];  // 32 KB total
    __shared__ float sD[TM];
    __shared__ int   sCI[TM];

    const int t = threadIdx.x;
    const int l = t & 63, w = t >> 6;
    const int wRow = (w >> 1) * 32;      // 0 or 32
    const int wCol = (w & 1) * 64;       // 0 or 64
    const int lr = l & 15, lg = l >> 4;
    const long long R0 = (long long)blockIdx.x * TM;

    // ---- per-row metadata ----
    if (t < TM) {
        long long Rs = R0 + t;
        int bb = Rs >= NF;
        int nn = (int)(Rs - (long long)bb * NF);
        sCI[t] = f2c[nn];
        sD[t]  = dist[nn];
    }
    __syncthreads();                               // barrier 1

    const f16* WT1 = ws;
    const f16* WT2 = ws + 32768;
    const f16* WT3 = ws + 49152;

    // ---- layer 1: acc = b1 + d*W1[256] + concat(xg,xs) @ W1[0:256] ----
    f32x4 acc[2][4];
    #pragma unroll
    for (int nt = 0; nt < 4; ++nt) {
        int col = wCol + nt * 16 + lr;
        float bc = b1[col];
        float wc = W1[256 * H + col];
        #pragma unroll
        for (int mt = 0; mt < 2; ++mt)
            #pragma unroll
            for (int r = 0; r < 4; ++r)
                acc[mt][nt][r] = bc + sD[wRow + mt * 16 + lg * 4 + r] * wc;
    }

    // this lane's two A-rows
    const long long Rs0 = R0 + wRow + lr;
    const long long Rs1 = R0 + wRow + 16 + lr;
    const int bb0 = Rs0 >= NF, bb1 = Rs1 >= NF;
    const float* xg0 = x + ((long long)bb0 * NC + sCI[wRow + lr]) * H;
    const float* xg1 = x + ((long long)bb1 * NC + sCI[wRow + 16 + lr]) * H;
    const float* xs0 = xsc + Rs0 * H;
    const float* xs1 = xsc + Rs1 * H;

    // xg part: W1^T k in [0,128)
    #pragma unroll 2
    for (int kk = 0; kk < 4; ++kk) {
        const int kc = kk * 32 + (lg << 3);        // col in source row & k in W1T
        f16x8 a0h, a0l, a1h, a1l;
        split8(*(const float4*)(xg0 + kc), *(const float4*)(xg0 + kc + 4), a0h, a0l);
        split8(*(const float4*)(xg1 + kc), *(const float4*)(xg1 + kc + 4), a1h, a1l);
        #pragma unroll
        for (int nt = 0; nt < 4; ++nt) {
            int off = (wCol + nt * 16 + lr) * 256 + kc;
            f16x8 wv = *(const f16x8*)(WT1 + off);
            acc[0][nt] = MFMA16(a0h, wv, acc[0][nt]);
            acc[0][nt] = MFMA16(a0l, wv, acc[0][nt]);
            acc[1][nt] = MFMA16(a1h, wv, acc[1][nt]);
            acc[1][nt] = MFMA16(a1l, wv, acc[1][nt]);
        }
    }
    // xs part: W1^T k in [128,256)
    #pragma unroll 2
    for (int kk = 0; kk < 4; ++kk) {
        const int kc = kk * 32 + (lg << 3);
        f16x8 a0h, a0l, a1h, a1l;
        split8(*(const float4*)(xs0 + kc), *(const float4*)(xs0 + kc + 4), a0h, a0l);
        split8(*(const float4*)(xs1 + kc), *(const float4*)(xs1 + kc + 4), a1h, a1l);
        #pragma unroll
        for (int nt = 0; nt < 4; ++nt) {
            int off = (wCol + nt * 16 + lr) * 256 + 128 + kc;
            f16x8 wv = *(const f16x8*)(WT1 + off);
            acc[0][nt] = MFMA16(a0h, wv, acc[0][nt]);
            acc[0][nt] = MFMA16(a0l, wv, acc[0][nt]);
            acc[1][nt] = MFMA16(a1h, wv, acc[1][nt]);
            acc[1][nt] = MFMA16(a1l, wv, acc[1][nt]);
        }
    }

    store_h(acc, sHh, sHl, wRow, wCol, lr, lg);    // h1 -> sH (first write, no reader yet)
    __syncthreads();                               // barrier 2: h1 visible

    // ---- layer 2 ----
    #pragma unroll
    for (int nt = 0; nt < 4; ++nt) {
        float bc = b2[wCol + nt * 16 + lr];
        #pragma unroll
        for (int mt = 0; mt < 2; ++mt)
            #pragma unroll
            for (int r = 0; r < 4; ++r)
                acc[mt][nt][r] = bc;
    }
    gemm2_lds(sHh, sHl, WT2, wRow, wCol, lr, lg, acc);
    __syncthreads();                               // barrier 3: all done reading h1

    store_h(acc, sHh, sHl, wRow, wCol, lr, lg);    // h2 -> sH
    __syncthreads();                               // barrier 4: h2 visible

    // ---- layer 3 ----
    #pragma unroll
    for (int nt = 0; nt < 4; ++nt) {
        float bc = b3[wCol + nt * 16 + lr];
        #pragma unroll
        for (int mt = 0; mt < 2; ++mt)
            #pragma unroll
            for (int r = 0; r < 4; ++r)
                acc[mt][nt][r] = bc;
    }
    gemm2_lds(sHh, sHl, WT3, wRow, wCol, lr, lg, acc);

    // ---- store out ----
    #pragma unroll
    for (int mt = 0; mt < 2; ++mt)
        #pragma unroll
        for (int nt = 0; nt < 4; ++nt)
            #pragma unroll
            for (int r = 0; r < 4; ++r) {
                long long row = R0 + wRow + mt * 16 + lg * 4 + r;
                int col = wCol + nt * 16 + lr;
                out[row * H + col] = acc[mt][nt][r];
            }
}

extern "C" void kernel_launch(void* const* d_in, const int* in_sizes, int n_in,
                              void* d_out, int out_size, void* d_ws, size_t ws_size,
                              hipStream_t stream)
{
    const float* x    = (const float*)d_in[0];
    const float* xsc  = (const float*)d_in[1];
    const int*   f2c  = (const int*)d_in[2];
    const float* dist = (const float*)d_in[3];
    const float* W1   = (const float*)d_in[4];
    const float* b1   = (const float*)d_in[5];
    const float* W2   = (const float*)d_in[6];
    const float* b2   = (const float*)d_in[7];
    const float* W3   = (const float*)d_in[8];
    const float* b3   = (const float*)d_in[9];
    f16* ws = (f16*)d_ws;

    prep_w<<<256, 256, 0, stream>>>(W1, W2, W3, ws);

    const int n_rows = 2 * NF;                    // 200000
    dim3 grid(n_rows / TM);                       // 3125
    fused_mlp_mfma<<<grid, 256, 0, stream>>>(x, xsc, f2c, dist, W1, b1, b2, b3,
                                             ws, (float*)d_out);
}